// Round 1
// baseline (1350.813 us; speedup 1.0000x reference)
//
#include <hip/hip_runtime.h>

#define NB 4          // nodes per workgroup
#define OUT0 8388608  // N*F floats: start of ST region in d_out

typedef __attribute__((ext_vector_type(8))) short sh8;
typedef __attribute__((ext_vector_type(4))) short sh4;
typedef __attribute__((ext_vector_type(4))) float fl4;

__device__ __forceinline__ unsigned short f2bf(float f) {
    unsigned int u = __builtin_bit_cast(unsigned int, f);
    u += 0x7FFFu + ((u >> 16) & 1u);               // round-to-nearest-even
    return (unsigned short)(u >> 16);
}
__device__ __forceinline__ float bf2f(unsigned short s) {
    unsigned int u = ((unsigned int)s) << 16;
    return __builtin_bit_cast(float, u);
}

// Swizzled element offsets (elements are ushort/bf16).
// A-type tiles [64 rows][256 cols]: row-major, XOR-swizzle keeps ds_read_b128 ~2-way.
#define EA(r,c) (((r)<<8) + ((c) ^ (((r)&7)<<3)))
// v_T tile [256 chan][64 rows]
#define EV(c,r) (((c)<<6) + ((r) ^ (((c)&7)<<3)))
// attn tile per wave: [16 qt][40] (32 kt + pad; kt>=16 stays zero => PV A-frag padding)
#define ET(w,qt,kt) ((w)*640 + (qt)*40 + (kt))

__global__ void setup_kernel(const float* __restrict__ Wq, const float* __restrict__ Wk,
                             const float* __restrict__ Wv, const float* __restrict__ lw,
                             unsigned short* __restrict__ wsW) {
    int tid = blockIdx.x * blockDim.x + threadIdx.x;   // 65536 threads
    int c = tid >> 8, k = tid & 255;
    wsW[tid]          = f2bf(Wq[k * 256 + c]);   // WqT[c][k]
    wsW[65536 + tid]  = f2bf(Wk[k * 256 + c]);   // WkT[c][k]
    wsW[131072 + tid] = f2bf(Wv[k * 256 + c]);   // WvT[c][k]
    wsW[196608 + tid] = f2bf(lw[tid]);           // lin_w[o][i] row-major (already B-friendly)
}

// C[64x256] = A(lds,64x256) @ W(global bf16, [col][k] layout, 256x256)
// wave w owns col-tiles w*4..w*4+3, all 4 row-tiles (B-frag reuse x4).
__device__ __forceinline__ void gemm64x256(const unsigned short* A,
                                           const unsigned short* __restrict__ W,
                                           int w, int l, fl4 acc[4][4]) {
    const int qd = l >> 4, c16 = l & 15;
#pragma unroll
    for (int kb = 0; kb < 8; ++kb) {
        sh8 bfr[4], afr[4];
#pragma unroll
        for (int ci = 0; ci < 4; ++ci) {
            int col = (w * 4 + ci) * 16 + c16;
            bfr[ci] = *(const sh8*)(W + col * 256 + kb * 32 + qd * 8);
        }
#pragma unroll
        for (int rt = 0; rt < 4; ++rt)
            afr[rt] = *(const sh8*)(A + EA(rt * 16 + c16, kb * 32 + qd * 8));
#pragma unroll
        for (int ci = 0; ci < 4; ++ci)
#pragma unroll
            for (int rt = 0; rt < 4; ++rt)
                acc[ci][rt] = __builtin_amdgcn_mfma_f32_16x16x32_bf16(
                    afr[rt], bfr[ci], acc[ci][rt], 0, 0, 0);
    }
}

__launch_bounds__(256, 1)
__global__ void fused_kernel(const float* __restrict__ inputs, const float* __restrict__ EC,
                             const float* __restrict__ pos_emb, const float* __restrict__ lin_b,
                             const unsigned short* __restrict__ wsW,
                             float* __restrict__ d_out) {
    extern __shared__ char smem[];
    unsigned short* bufA  = (unsigned short*)smem;   // temporal -> later ctx   [64][256]
    unsigned short* bufB  = bufA + 16384;            // EC -> later v_T [256][64]
    unsigned short* bufC  = bufB + 16384;            // k  [64][256]
    unsigned short* bufD  = bufC + 16384;            // q  [64][256]
    unsigned short* attnL = bufD + 16384;            // 4 x [16][40] bf16 (5120 B)
    float*          outL  = (float*)(attnL + 2560);  // [4][256] f32 (4096 B)

    const int tid = threadIdx.x;
    const int w = tid >> 6, l = tid & 63;
    const int qd = l >> 4, c16 = l & 15;
    const int n0 = blockIdx.x * NB;

    // zero attn buffers once (upper kt-half must stay zero: PV K-padding)
    for (int z = tid; z < 320; z += 256) ((fl4*)attnL)[z] = (fl4){0.f, 0.f, 0.f, 0.f};

    // ---- stage temporal=(inputs+pos_emb) -> bufA, EC -> bufB (f32 -> bf16) ----
#pragma unroll
    for (int i = 0; i < 16; ++i) {
        int row = i * 4 + w;                       // 64 rows, 1 row per wave per iter
        size_t g = ((size_t)n0 * 16 + row) * 256 + 4 * l;
        fl4 in4 = *(const fl4*)(inputs + g);
        fl4 pe4 = *(const fl4*)(pos_emb + (row & 15) * 256 + 4 * l);
        fl4 ec4 = *(const fl4*)(EC + g);
        sh4 tb, eb;
#pragma unroll
        for (int j = 0; j < 4; ++j) {
            tb[j] = (short)f2bf(in4[j] + pe4[j]);
            eb[j] = (short)f2bf(ec4[j]);
        }
        *(sh4*)(bufA + EA(row, 4 * l)) = tb;
        *(sh4*)(bufB + EA(row, 4 * l)) = eb;
    }
    __syncthreads();

    // ---- tmean -> outL (out = mean_T(ff+temporal) = mean_T(relu+ctx) + tmean) ----
    {
        fl4 tm = {0.f, 0.f, 0.f, 0.f};
#pragma unroll
        for (int t = 0; t < 16; ++t) {
            sh4 v = *(const sh4*)(bufA + EA(w * 16 + t, 4 * l));
#pragma unroll
            for (int j = 0; j < 4; ++j) tm[j] += bf2f((unsigned short)v[j]);
        }
        tm *= 0.0625f;
        *(fl4*)(outL + w * 256 + 4 * l) = tm;
    }

    // ---- k = EC @ Wk -> bufC ----
    {
        fl4 acc[4][4] = {};
        gemm64x256(bufB, wsW + 65536, w, l, acc);
#pragma unroll
        for (int ci = 0; ci < 4; ++ci) {
            int col = (w * 4 + ci) * 16 + c16;
#pragma unroll
            for (int rt = 0; rt < 4; ++rt)
#pragma unroll
                for (int i2 = 0; i2 < 4; ++i2)
                    bufC[EA(rt * 16 + qd * 4 + i2, col)] = f2bf(acc[ci][rt][i2]);
        }
    }
    // ---- q = temporal @ Wq -> bufD ----
    {
        fl4 acc[4][4] = {};
        gemm64x256(bufA, wsW, w, l, acc);
#pragma unroll
        for (int ci = 0; ci < 4; ++ci) {
            int col = (w * 4 + ci) * 16 + c16;
#pragma unroll
            for (int rt = 0; rt < 4; ++rt)
#pragma unroll
                for (int i2 = 0; i2 < 4; ++i2)
                    bufD[EA(rt * 16 + qd * 4 + i2, col)] = f2bf(acc[ci][rt][i2]);
        }
    }
    __syncthreads();   // all bufB (EC) reads done before v_T overwrites it

    // ---- v = temporal @ Wv -> v_T in bufB ----
    {
        fl4 acc[4][4] = {};
        gemm64x256(bufA, wsW + 131072, w, l, acc);
#pragma unroll
        for (int ci = 0; ci < 4; ++ci) {
            int col = (w * 4 + ci) * 16 + c16;
#pragma unroll
            for (int rt = 0; rt < 4; ++rt)
#pragma unroll
                for (int i2 = 0; i2 < 4; ++i2)
                    bufB[EV(col, rt * 16 + qd * 4 + i2)] = f2bf(acc[ci][rt][i2]);
        }
    }
    __syncthreads();   // q,k,v_T ready; bufA (temporal) now dead -> reuse for ctx

    // ---- attention: wave w owns node n0+w ----
    const size_t STbase = (size_t)OUT0 + (size_t)(n0 + w) * 4096;
    for (int h = 0; h < 16; ++h) {
        sh8 zero8 = {};
        // scores S = q_h @ k_h^T  (K=16 padded to 32; zero A-frag on lanes>=32)
        sh8 qa = *(const sh8*)(bufD + EA(w * 16 + c16, h * 16 + (qd & 1) * 8));
        sh8 ka = *(const sh8*)(bufC + EA(w * 16 + c16, h * 16 + (qd & 1) * 8));
        if (l >= 32) qa = zero8;   // zero A kills garbage B positions too
        fl4 s = {};
        s = __builtin_amdgcn_mfma_f32_16x16x32_bf16(qa, ka, s, 0, 0, 0);

        float p[4];
#pragma unroll
        for (int i2 = 0; i2 < 4; ++i2) {
            float v = s[i2] * 0.25f;            // 1/sqrt(T)
            float m = v;
            m = fmaxf(m, __shfl_xor(m, 1));
            m = fmaxf(m, __shfl_xor(m, 2));
            m = fmaxf(m, __shfl_xor(m, 4));
            m = fmaxf(m, __shfl_xor(m, 8));
            float e = __expf(v - m);
            float su = e;
            su += __shfl_xor(su, 1);
            su += __shfl_xor(su, 2);
            su += __shfl_xor(su, 4);
            su += __shfl_xor(su, 8);
            p[i2] = __fdividef(e, su);
        }
        // ST[n, qt, h*16+kt] stores (16-lane groups are 64B-contiguous) + attn->LDS bf16
#pragma unroll
        for (int i2 = 0; i2 < 4; ++i2) {
            d_out[STbase + (size_t)(qd * 4 + i2) * 256 + h * 16 + c16] = p[i2];
            attnL[ET(w, qd * 4 + i2, c16)] = f2bf(p[i2]);
        }
        asm volatile("s_waitcnt lgkmcnt(0)" ::: "memory");  // cross-lane LDS visibility in-wave

        // ctx_h = P @ v_h : A=attn (kt>=16 rows are persistent zeros), B=v_T
        sh8 pa = *(const sh8*)(attnL + ET(w, c16, qd * 8));
        sh8 vb = *(const sh8*)(bufB + EV(h * 16 + c16, w * 16 + (qd & 1) * 8));
        fl4 cx = {};
        cx = __builtin_amdgcn_mfma_f32_16x16x32_bf16(pa, vb, cx, 0, 0, 0);
#pragma unroll
        for (int i2 = 0; i2 < 4; ++i2)
            bufA[EA(w * 16 + qd * 4 + i2, h * 16 + c16)] = f2bf(cx[i2]);
    }
    __syncthreads();   // ctx (bufA) fully written by all waves

    // ---- ff = relu(ctx@lin_w^T + b) + ctx ; accumulate mean over T into outL ----
    {
        fl4 acc[4][4] = {};
        gemm64x256(bufA, wsW + 196608, w, l, acc);
#pragma unroll
        for (int ci = 0; ci < 4; ++ci) {
            int col = (w * 4 + ci) * 16 + c16;
            float bias = lin_b[col];
#pragma unroll
            for (int rt = 0; rt < 4; ++rt) {
                float ssum = 0.f;
#pragma unroll
                for (int i2 = 0; i2 < 4; ++i2) {
                    float ffv = fmaxf(acc[ci][rt][i2] + bias, 0.f);
                    float cxv = bf2f(bufA[EA(rt * 16 + qd * 4 + i2, col)]);
                    ssum += ffv + cxv;
                }
                ssum += __shfl_xor(ssum, 16);   // sum the 4 qd row-groups -> all 16 t
                ssum += __shfl_xor(ssum, 32);
                if (l < 16) outL[rt * 256 + col] += ssum * 0.0625f;
            }
        }
    }
    __syncthreads();

    // ---- write out[n][c] ----
    {
        fl4 o = *(const fl4*)(outL + w * 256 + 4 * l);
        *(fl4*)(d_out + (size_t)(n0 + w) * 256 + 4 * l) = o;
    }
}

extern "C" void kernel_launch(void* const* d_in, const int* in_sizes, int n_in,
                              void* d_out, int out_size, void* d_ws, size_t ws_size,
                              hipStream_t stream) {
    const float* inputs = (const float*)d_in[0];
    const float* EC     = (const float*)d_in[1];
    const float* pos    = (const float*)d_in[2];
    const float* Wq     = (const float*)d_in[3];
    const float* Wk     = (const float*)d_in[4];
    const float* Wv     = (const float*)d_in[5];
    const float* lw     = (const float*)d_in[6];
    const float* lb     = (const float*)d_in[7];
    unsigned short* wsW = (unsigned short*)d_ws;   // 4 x 65536 bf16 = 512 KB
    float* out = (float*)d_out;

    (void)hipFuncSetAttribute(reinterpret_cast<const void*>(fused_kernel),
                              hipFuncAttributeMaxDynamicSharedMemorySize, 140288);

    setup_kernel<<<256, 256, 0, stream>>>(Wq, Wk, Wv, lw, wsW);
    fused_kernel<<<8192, 256, 140288, stream>>>(inputs, EC, pos, lb, wsW, out);
}

// Round 2
// 1129.093 us; speedup vs baseline: 1.1964x; 1.1964x over previous
//
#include <hip/hip_runtime.h>

#define OUT0 8388608   // N*F floats: start of ST region in d_out

typedef __attribute__((ext_vector_type(8))) short sh8;
typedef __attribute__((ext_vector_type(4))) short sh4;
typedef __attribute__((ext_vector_type(4))) float fl4;

__device__ __forceinline__ unsigned short f2bf(float f) {
    unsigned int u = __builtin_bit_cast(unsigned int, f);
    u += 0x7FFFu + ((u >> 16) & 1u);               // round-to-nearest-even
    return (unsigned short)(u >> 16);
}
__device__ __forceinline__ float bf2f(unsigned short s) {
    unsigned int u = ((unsigned int)s) << 16;
    return __builtin_bit_cast(float, u);
}

// [32 rows][256 cols] bf16 tile, XOR-swizzled for conflict-free ds_read_b128
#define EA(r,c) (((r)<<8) + ((c) ^ (((r)&7)<<3)))
// v_T tile [256 chan][32 rows]
#define EV(c,r) (((c)<<5) + ((r) ^ (((c)&3)<<3)))

__global__ void setup_kernel(const float* __restrict__ Wq, const float* __restrict__ Wk,
                             const float* __restrict__ Wv, const float* __restrict__ lw,
                             unsigned short* __restrict__ wsW) {
    int tid = blockIdx.x * blockDim.x + threadIdx.x;   // 65536 threads
    int c = tid >> 8, k = tid & 255;
    wsW[tid]          = f2bf(Wq[k * 256 + c]);   // WqT[c][k]
    wsW[65536 + tid]  = f2bf(Wk[k * 256 + c]);   // WkT[c][k]
    wsW[131072 + tid] = f2bf(Wv[k * 256 + c]);   // WvT[c][k]
    wsW[196608 + tid] = f2bf(lw[tid]);           // lin_w[o][i] row-major (B-friendly)
}

// acc[4][2] += A(lds [32][256]) @ W(global bf16 [col][k]); wave w owns cols w*64..w*64+63
__device__ __forceinline__ void gemm32x256(const unsigned short* A,
                                           const unsigned short* __restrict__ W,
                                           int w, int l, fl4 acc[4][2]) {
    const int qd = l >> 4, c16 = l & 15;
#pragma unroll
    for (int kb = 0; kb < 8; ++kb) {
        sh8 afr[2];
#pragma unroll
        for (int rt = 0; rt < 2; ++rt)
            afr[rt] = *(const sh8*)(A + EA(rt * 16 + c16, kb * 32 + qd * 8));
#pragma unroll
        for (int ci = 0; ci < 4; ++ci) {
            int col = w * 64 + ci * 16 + c16;
            sh8 bfr = *(const sh8*)(W + col * 256 + kb * 32 + qd * 8);
#pragma unroll
            for (int rt = 0; rt < 2; ++rt)
                acc[ci][rt] = __builtin_amdgcn_mfma_f32_16x16x32_bf16(
                    afr[rt], bfr, acc[ci][rt], 0, 0, 0);
        }
    }
}

__launch_bounds__(256, 3)
__global__ void fused_kernel(const float* __restrict__ inputs, const float* __restrict__ EC,
                             const float* __restrict__ pos_emb, const float* __restrict__ lin_b,
                             const unsigned short* __restrict__ wsW,
                             float* __restrict__ d_out) {
    extern __shared__ char smem[];
    unsigned short* X = (unsigned short*)smem;   // temporal -> v_T      [32][256] / [256][32]
    unsigned short* Y = X + 8192;                // EC -> k -> P(attn)   [32][256]
    unsigned short* Z = Y + 8192;                // q -> ctx             [32][256]
    float*       outL = (float*)(Z + 8192);      // [2][256] f32

    const int tid = threadIdx.x;
    const int w = tid >> 6, l = tid & 63;
    const int qd = l >> 4, c16 = l & 15;
    const size_t rbase = (size_t)blockIdx.x * 32;   // global row base (node-major rows)
    const int n0 = blockIdx.x * 2;

    // ---- stage temporal=(inputs+pos_emb) -> X, EC -> Y ----
#pragma unroll
    for (int i = 0; i < 8; ++i) {
        int row = i * 4 + w;
        size_t g = (rbase + row) * 256 + 4 * l;
        fl4 in4 = *(const fl4*)(inputs + g);
        fl4 pe4 = *(const fl4*)(pos_emb + (row & 15) * 256 + 4 * l);
        fl4 ec4 = *(const fl4*)(EC + g);
        sh4 tb, eb;
#pragma unroll
        for (int j = 0; j < 4; ++j) {
            tb[j] = (short)f2bf(in4[j] + pe4[j]);
            eb[j] = (short)f2bf(ec4[j]);
        }
        *(sh4*)(X + EA(row, 4 * l)) = tb;
        *(sh4*)(Y + EA(row, 4 * l)) = eb;
    }
    __syncthreads();                               // B1

    // ---- tmean -> outL (out = mean_T(relu+ctx) + mean_T(temporal)) ----
#pragma unroll
    for (int nd = 0; nd < 2; ++nd) {
        float s = 0.f;
#pragma unroll
        for (int t = 0; t < 16; ++t) s += bf2f(X[EA(nd * 16 + t, tid)]);
        outL[nd * 256 + tid] = s * 0.0625f;
    }

    // ---- k = EC@Wk (in-place to Y), q = temporal@Wq (to Z) ----
    {
        fl4 aK[4][2] = {}, aQ[4][2] = {};
        gemm32x256(Y, wsW + 65536, w, l, aK);
        gemm32x256(X, wsW, w, l, aQ);
        __syncthreads();                           // B2: all X/Y reads done
#pragma unroll
        for (int ci = 0; ci < 4; ++ci) {
            int col = w * 64 + ci * 16 + c16;
#pragma unroll
            for (int rt = 0; rt < 2; ++rt)
#pragma unroll
                for (int i2 = 0; i2 < 4; ++i2) {
                    Y[EA(rt * 16 + qd * 4 + i2, col)] = f2bf(aK[ci][rt][i2]);
                    Z[EA(rt * 16 + qd * 4 + i2, col)] = f2bf(aQ[ci][rt][i2]);
                }
        }
    }
    __syncthreads();                               // B3: k,q ready

    // ---- QK^T + softmax (wave w: node w>>1, heads (w&1)*8..+7) ----
    const int nd = w >> 1, hb = (w & 1) * 8;
    unsigned short pb[32];
    {
        fl4 s[8];
#pragma unroll
        for (int h = 0; h < 8; ++h) {
            sh8 qa = {}, ka = {};
            if (l < 32) {                          // K=16 padded to 32: zero A upper half
                qa = *(const sh8*)(Z + EA(nd * 16 + c16, (hb + h) * 16 + qd * 8));
                ka = *(const sh8*)(Y + EA(nd * 16 + c16, (hb + h) * 16 + qd * 8));
            }
            fl4 z = {};
            s[h] = __builtin_amdgcn_mfma_f32_16x16x32_bf16(qa, ka, z, 0, 0, 0);
        }
#pragma unroll
        for (int h = 0; h < 8; ++h)
#pragma unroll
            for (int i2 = 0; i2 < 4; ++i2) {
                float v = s[h][i2] * 0.25f;        // 1/sqrt(T)
                float m = v;
                m = fmaxf(m, __shfl_xor(m, 1));
                m = fmaxf(m, __shfl_xor(m, 2));
                m = fmaxf(m, __shfl_xor(m, 4));
                m = fmaxf(m, __shfl_xor(m, 8));
                float e = __expf(v - m);
                float su = e;
                su += __shfl_xor(su, 1);
                su += __shfl_xor(su, 2);
                su += __shfl_xor(su, 4);
                su += __shfl_xor(su, 8);
                pb[h * 4 + i2] = f2bf(__fdividef(e, su));
            }
    }

    // ---- v = temporal@Wv (acc only; X still needed as read source) ----
    fl4 aV[4][2] = {};
    gemm32x256(X, wsW + 131072, w, l, aV);
    __syncthreads();                               // B4: all k(Y)/temporal(X) reads done

    // ---- write P -> Y (ST layout), v_T -> X ----
#pragma unroll
    for (int h = 0; h < 8; ++h)
#pragma unroll
        for (int i2 = 0; i2 < 4; ++i2)
            Y[EA(nd * 16 + qd * 4 + i2, (hb + h) * 16 + c16)] = pb[h * 4 + i2];
#pragma unroll
    for (int ci = 0; ci < 4; ++ci) {
        int col = w * 64 + ci * 16 + c16;
#pragma unroll
        for (int rt = 0; rt < 2; ++rt)
#pragma unroll
            for (int i2 = 0; i2 < 4; ++i2)
                X[EV(col, rt * 16 + qd * 4 + i2)] = f2bf(aV[ci][rt][i2]);
    }
    __syncthreads();                               // B5: P, v_T ready

    // ---- PV: ctx -> Z (q dead) ----
#pragma unroll
    for (int h = 0; h < 8; ++h) {
        sh8 pa = {};
        if (l < 32)
            pa = *(const sh8*)(Y + EA(nd * 16 + c16, (hb + h) * 16 + qd * 8));
        sh8 vb = *(const sh8*)(X + EV((hb + h) * 16 + c16, nd * 16 + (qd & 1) * 8));
        fl4 z = {};
        fl4 cx = __builtin_amdgcn_mfma_f32_16x16x32_bf16(pa, vb, z, 0, 0, 0);
#pragma unroll
        for (int i2 = 0; i2 < 4; ++i2)
            Z[EA(nd * 16 + qd * 4 + i2, (hb + h) * 16 + c16)] = f2bf(cx[i2]);
    }

    // ---- ST dump: Y is already [node][qt][h*16+kt] => fully coalesced fl4 stores ----
#pragma unroll
    for (int ch = 0; ch < 8; ++ch) {
        int flat = ch * 1024 + tid * 4;
        int row = flat >> 8, col = flat & 255;
        sh4 pv = *(const sh4*)(Y + (row << 8) + (col ^ ((row & 7) << 3)));
        fl4 o;
#pragma unroll
        for (int j = 0; j < 4; ++j) o[j] = bf2f((unsigned short)pv[j]);
        *(fl4*)(d_out + OUT0 + (size_t)blockIdx.x * 8192 + flat) = o;
    }
    __syncthreads();                               // B6: ctx(Z) ready

    // ---- ff = relu(ctx@lin_w^T + b) + ctx; mean over T into outL ----
    {
        fl4 aF[4][2] = {};
        gemm32x256(Z, wsW + 196608, w, l, aF);
#pragma unroll
        for (int ci = 0; ci < 4; ++ci) {
            int col = w * 64 + ci * 16 + c16;
            float bias = lin_b[col];
#pragma unroll
            for (int rt = 0; rt < 2; ++rt) {
                float ssum = 0.f;
#pragma unroll
                for (int i2 = 0; i2 < 4; ++i2) {
                    float ffv = fmaxf(aF[ci][rt][i2] + bias, 0.f);
                    float cxv = bf2f(Z[EA(rt * 16 + qd * 4 + i2, col)]);
                    ssum += ffv + cxv;
                }
                ssum += __shfl_xor(ssum, 16);      // sum 4 qd row-groups -> all 16 t
                ssum += __shfl_xor(ssum, 32);
                if (l < 16) outL[rt * 256 + col] += ssum * 0.0625f;
            }
        }
    }
    __syncthreads();                               // B7

    // ---- write out[n][c] ----
    if (tid < 128) {
        int idx = tid * 4;
        fl4 o = *(const fl4*)(outL + idx);
        *(fl4*)(d_out + (size_t)n0 * 256 + idx) = o;
    }
}

extern "C" void kernel_launch(void* const* d_in, const int* in_sizes, int n_in,
                              void* d_out, int out_size, void* d_ws, size_t ws_size,
                              hipStream_t stream) {
    const float* inputs = (const float*)d_in[0];
    const float* EC     = (const float*)d_in[1];
    const float* Wq     = (const float*)d_in[3];
    const float* Wk     = (const float*)d_in[4];
    const float* Wv     = (const float*)d_in[5];
    const float* lw     = (const float*)d_in[6];
    const float* lb     = (const float*)d_in[7];
    const float* pos    = (const float*)d_in[2];
    unsigned short* wsW = (unsigned short*)d_ws;   // 4 x 65536 bf16 = 512 KB
    float* out = (float*)d_out;

    (void)hipFuncSetAttribute(reinterpret_cast<const void*>(fused_kernel),
                              hipFuncAttributeMaxDynamicSharedMemorySize, 51200);

    setup_kernel<<<256, 256, 0, stream>>>(Wq, Wk, Wv, lw, wsW);
    fused_kernel<<<16384, 256, 51200, stream>>>(inputs, EC, pos, lb, wsW, out);
}